// Round 2
// baseline (27.815 us; speedup 1.0000x reference)
//
#include <hip/hip_runtime.h>
#include <math.h>

// Shapes fixed by setup_inputs(): rep_anchor [B,M,D] f32, rep_pos/neg [B,D] f32.
// Algebraic note: ed_self(anchor) cancels in (distance_pos - distance_neg),
// so only the two cross-energies are computed (one streaming pass of anchor).
constexpr int B = 16;
constexpr int M = 2048;
constexpr int D = 256;
constexpr float MARGIN = 5.0f;

constexpr int CHUNKS = 64;              // blocks per batch element
constexpr int GRID   = B * CHUNKS;      // 1024 blocks (4/CU), power of two (mod-trick needs it)
constexpr int RPB    = M / CHUNKS;      // 32 rows per block
constexpr int RPW    = RPB / 4;         // 8 rows per wave
constexpr int ITERS  = RPW / 4;         // 2 macro-iters (4 rows concurrently per wave)

// 256 threads = 4 waves. Within a wave, each 16-lane group owns one row:
// lane q of group g reads columns {c*64 + q*4 .. +3}, c = 0..3 (256 B
// contiguous per group per load). Per-lane accumulate, then a single 4-stage
// width-16 butterfly reduces all 4 rows of the wave simultaneously.

__global__ __launch_bounds__(256) void triplet_fused_kernel(
    const float* __restrict__ anchor,    // [B*M*D]
    const float* __restrict__ pos,       // [B*D]
    const float* __restrict__ neg,       // [B*D]
    float* __restrict__ partial,         // [B*CHUNKS*2]
    unsigned int* __restrict__ counter,  // 1 uint; never reset (mod-GRID trick)
    float* __restrict__ out)             // [1]
{
    const int b     = blockIdx.x >> 6;            // / CHUNKS
    const int chunk = blockIdx.x & (CHUNKS - 1);
    const int tid   = threadIdx.x;
    const int lane  = tid & 63;
    const int wave  = tid >> 6;
    const int g     = lane >> 4;                  // group within wave (row selector)
    const int q     = lane & 15;                  // lane within group (column selector)

    // pos/neg slices matching this lane's column pattern (reused for all rows)
    float4 p[4], n[4];
#pragma unroll
    for (int c = 0; c < 4; ++c) {
        p[c] = *reinterpret_cast<const float4*>(pos + b * D + c * 64 + q * 4);
        n[c] = *reinterpret_cast<const float4*>(neg + b * D + c * 64 + q * 4);
    }

    float accp = 0.0f, accn = 0.0f;
#pragma unroll
    for (int i = 0; i < ITERS; ++i) {
        const int r = chunk * RPB + wave * RPW + i * 4 + g;
        const float* arow = anchor + ((size_t)b * M + r) * (size_t)D;
        float4 a[4];
#pragma unroll
        for (int c = 0; c < 4; ++c)
            a[c] = *reinterpret_cast<const float4*>(arow + c * 64 + q * 4);

        float dp = 0.0f, dn = 0.0f;
#pragma unroll
        for (int c = 0; c < 4; ++c) {
            float t;
            t = a[c].x - p[c].x; dp = fmaf(t, t, dp);
            t = a[c].y - p[c].y; dp = fmaf(t, t, dp);
            t = a[c].z - p[c].z; dp = fmaf(t, t, dp);
            t = a[c].w - p[c].w; dp = fmaf(t, t, dp);
            t = a[c].x - n[c].x; dn = fmaf(t, t, dn);
            t = a[c].y - n[c].y; dn = fmaf(t, t, dn);
            t = a[c].z - n[c].z; dn = fmaf(t, t, dn);
            t = a[c].w - n[c].w; dn = fmaf(t, t, dn);
        }
        // 4-stage butterfly within each 16-lane group (4 rows reduce at once)
#pragma unroll
        for (int m = 8; m; m >>= 1) {
            dp += __shfl_xor(dp, m, 16);
            dn += __shfl_xor(dn, m, 16);
        }
        // all 16 lanes of the group now hold the same row sum (exact >= 0)
        accp += sqrtf(dp);
        accn += sqrtf(dn);
    }

    // ---- block reduce: one value per (wave, group) ----
    __shared__ float sp[16], sn[16];
    __shared__ int lastFlag;
    if (q == 0) { sp[wave * 4 + g] = accp; sn[wave * 4 + g] = accn; }
    __syncthreads();

    if (tid == 0) {
        float tp = 0.0f, tn = 0.0f;
#pragma unroll
        for (int k = 0; k < 16; ++k) { tp += sp[k]; tn += sn[k]; }
        const int pi = (b * CHUNKS + chunk) * 2;
        __hip_atomic_store(&partial[pi],     tp, __ATOMIC_RELAXED, __HIP_MEMORY_SCOPE_AGENT);
        __hip_atomic_store(&partial[pi + 1], tn, __ATOMIC_RELAXED, __HIP_MEMORY_SCOPE_AGENT);
        __threadfence();  // release: partials visible before the count
        const unsigned old = atomicAdd(counter, 1u);
        // exactly one block per call sees old ≡ GRID-1 (mod GRID); works from
        // any starting counter value (0xAAAAAAAA poison included), no reset.
        lastFlag = ((old & (GRID - 1)) == (GRID - 1)) ? 1 : 0;
    }
    __syncthreads();
    if (!lastFlag) return;

    // ---- finalize (single block): reduce all partials, triplet loss ----
    __threadfence();  // acquire
    {
        const int bb = tid >> 4;   // batch 0..15 (16 threads each, within a wave)
        const int k  = tid & 15;
        float tp = 0.0f, tn = 0.0f;
#pragma unroll
        for (int j = 0; j < 4; ++j) {
            const int pi = (bb * CHUNKS + (k + j * 16)) * 2;
            tp += __hip_atomic_load(&partial[pi],     __ATOMIC_RELAXED, __HIP_MEMORY_SCOPE_AGENT);
            tn += __hip_atomic_load(&partial[pi + 1], __ATOMIC_RELAXED, __HIP_MEMORY_SCOPE_AGENT);
        }
#pragma unroll
        for (int m = 8; m; m >>= 1) {
            tp += __shfl_xor(tp, m, 16);
            tn += __shfl_xor(tn, m, 16);
        }
        __shared__ float losses[16];
        if (k == 0) {
            const float d = (2.0f / (float)M) * (tp - tn) + MARGIN;
            losses[bb] = d > 0.0f ? d : 0.0f;
        }
        __syncthreads();
        if (tid == 0) {
            float s = 0.0f;
#pragma unroll
            for (int j = 0; j < B; ++j) s += losses[j];
            out[0] = s / (float)B;
        }
    }
}

extern "C" void kernel_launch(void* const* d_in, const int* in_sizes, int n_in,
                              void* d_out, int out_size, void* d_ws, size_t ws_size,
                              hipStream_t stream) {
    const float* anchor = (const float*)d_in[0];  // [B, M, D]
    const float* pos    = (const float*)d_in[1];  // [B, D]
    const float* neg    = (const float*)d_in[2];  // [B, D]
    float* out = (float*)d_out;

    float* partial = (float*)d_ws;  // B*CHUNKS*2 floats = 8 KiB, fully rewritten each call
    unsigned int* counter = (unsigned int*)((char*)d_ws + (size_t)B * CHUNKS * 2 * sizeof(float));

    triplet_fused_kernel<<<GRID, 256, 0, stream>>>(anchor, pos, neg, partial, counter, out);
}

// Round 3
// 11.135 us; speedup vs baseline: 2.4981x; 2.4981x over previous
//
#include <hip/hip_runtime.h>
#include <math.h>

// Shapes fixed by setup_inputs(): rep_anchor [B,M,D] f32, rep_pos/neg [B,D] f32.
// Algebra: ed_self(anchor) cancels in (distance_pos - distance_neg), so only
// the two cross-energies are needed -> one streaming pass over anchor.
// NOTE (round-2 lesson): no device-scope atomics/fences for the combine —
// 1024 same-address cross-XCD RMWs cost ~40 µs. Two dispatches are cheaper.
constexpr int B = 16;
constexpr int M = 2048;
constexpr int D = 256;
constexpr float MARGIN = 5.0f;

constexpr int CHUNKS = 64;              // blocks per batch element
constexpr int GRID   = B * CHUNKS;      // 1024 blocks = 4/CU
constexpr int RPB    = M / CHUNKS;      // 32 rows per block
constexpr int RPW    = RPB / 4;         // 8 rows per wave
constexpr int ITERS  = RPW / 4;         // 2 macro-iters (4 rows in flight per wave)

// 256 threads = 4 waves. Within a wave, each 16-lane group owns one row:
// lane q of group g reads columns {c*64 + q*4 .. +3}, c=0..3 (256 B contiguous
// per group per load instruction). Per-lane accumulate, then ONE 4-stage
// width-16 butterfly reduces all 4 rows of the wave simultaneously
// (2 shuffles/row amortized vs 12/row for a naive 64-wide reduce).

__global__ __launch_bounds__(256) void cross_partial_kernel(
    const float* __restrict__ anchor,   // [B*M*D]
    const float* __restrict__ pos,      // [B*D]
    const float* __restrict__ neg,      // [B*D]
    float* __restrict__ partial)        // [B*CHUNKS*2] (sum_pos, sum_neg)
{
    const int b     = blockIdx.x >> 6;            // / CHUNKS
    const int chunk = blockIdx.x & (CHUNKS - 1);
    const int tid   = threadIdx.x;
    const int lane  = tid & 63;
    const int wave  = tid >> 6;
    const int g     = lane >> 4;                  // row selector within wave
    const int q     = lane & 15;                  // column selector within group

    // pos/neg slices matching this lane's column pattern (reused for all rows)
    float4 p[4], n[4];
#pragma unroll
    for (int c = 0; c < 4; ++c) {
        p[c] = *reinterpret_cast<const float4*>(pos + b * D + c * 64 + q * 4);
        n[c] = *reinterpret_cast<const float4*>(neg + b * D + c * 64 + q * 4);
    }

    float accp = 0.0f, accn = 0.0f;
#pragma unroll
    for (int i = 0; i < ITERS; ++i) {
        const int r = chunk * RPB + wave * RPW + i * 4 + g;
        const float* arow = anchor + ((size_t)b * M + r) * (size_t)D;
        float4 a[4];
#pragma unroll
        for (int c = 0; c < 4; ++c)
            a[c] = *reinterpret_cast<const float4*>(arow + c * 64 + q * 4);

        float dp = 0.0f, dn = 0.0f;
#pragma unroll
        for (int c = 0; c < 4; ++c) {
            float t;
            t = a[c].x - p[c].x; dp = fmaf(t, t, dp);
            t = a[c].y - p[c].y; dp = fmaf(t, t, dp);
            t = a[c].z - p[c].z; dp = fmaf(t, t, dp);
            t = a[c].w - p[c].w; dp = fmaf(t, t, dp);
            t = a[c].x - n[c].x; dn = fmaf(t, t, dn);
            t = a[c].y - n[c].y; dn = fmaf(t, t, dn);
            t = a[c].z - n[c].z; dn = fmaf(t, t, dn);
            t = a[c].w - n[c].w; dn = fmaf(t, t, dn);
        }
        // 4-stage butterfly within each 16-lane group (4 rows reduce at once)
#pragma unroll
        for (int m = 8; m; m >>= 1) {
            dp += __shfl_xor(dp, m, 16);
            dn += __shfl_xor(dn, m, 16);
        }
        // every lane of the group now holds the full row sum (exact, >= 0)
        accp += sqrtf(dp);
        accn += sqrtf(dn);
    }

    // block reduce: one value per (wave, group) -> 16 pairs -> 2 stores
    __shared__ float sp[16], sn[16];
    if (q == 0) { sp[wave * 4 + g] = accp; sn[wave * 4 + g] = accn; }
    __syncthreads();
    if (tid == 0) {
        float tp = 0.0f, tn = 0.0f;
#pragma unroll
        for (int k = 0; k < 16; ++k) { tp += sp[k]; tn += sn[k]; }
        const int pi = (b * CHUNKS + chunk) * 2;
        partial[pi + 0] = tp;
        partial[pi + 1] = tn;
    }
}

// Single block, 256 threads: 16 threads per batch element reduce its 64
// chunk-partials in parallel, width-16 butterfly, relu, mean over B.
__global__ __launch_bounds__(256) void finalize_kernel(
    const float* __restrict__ partial, float* __restrict__ out)
{
    const int tid = threadIdx.x;
    const int bb  = tid >> 4;   // batch 0..15
    const int k   = tid & 15;

    float tp = 0.0f, tn = 0.0f;
#pragma unroll
    for (int j = 0; j < 4; ++j) {
        const int pi = (bb * CHUNKS + (k + j * 16)) * 2;
        tp += partial[pi + 0];
        tn += partial[pi + 1];
    }
#pragma unroll
    for (int m = 8; m; m >>= 1) {
        tp += __shfl_xor(tp, m, 16);
        tn += __shfl_xor(tn, m, 16);
    }
    __shared__ float losses[16];
    if (k == 0) {
        const float d = (2.0f / (float)M) * (tp - tn) + MARGIN;
        losses[bb] = d > 0.0f ? d : 0.0f;
    }
    __syncthreads();
    if (tid == 0) {
        float s = 0.0f;
#pragma unroll
        for (int j = 0; j < B; ++j) s += losses[j];
        out[0] = s / (float)B;
    }
}

extern "C" void kernel_launch(void* const* d_in, const int* in_sizes, int n_in,
                              void* d_out, int out_size, void* d_ws, size_t ws_size,
                              hipStream_t stream) {
    const float* anchor = (const float*)d_in[0];  // [B, M, D]
    const float* pos    = (const float*)d_in[1];  // [B, D]
    const float* neg    = (const float*)d_in[2];  // [B, D]
    float* out = (float*)d_out;
    float* partial = (float*)d_ws;  // B*CHUNKS*2 floats = 8 KiB, fully rewritten each call

    cross_partial_kernel<<<GRID, 256, 0, stream>>>(anchor, pos, neg, partial);
    finalize_kernel<<<1, 256, 0, stream>>>(partial, out);
}